// Round 6
// baseline (409.878 us; speedup 1.0000x reference)
//
#include <hip/hip_runtime.h>
#include <hip/hip_bf16.h>

typedef unsigned short u16;
typedef __bf16 bf16x8 __attribute__((ext_vector_type(8)));
typedef float floatx4 __attribute__((ext_vector_type(4)));

#define B_ 4
#define N_ 2048
#define C_ 1024
#define H_ 16
#define HD_ 64

__device__ __forceinline__ float b2f(u16 u) {
    union { float f; unsigned int i; } v; v.i = ((unsigned int)u) << 16; return v.f;
}
__device__ __forceinline__ u16 f2b(float f) {
    union { float f; unsigned int i; } v; v.f = f;
    unsigned int i = v.i;
    unsigned int r = i + 0x7FFFu + ((i >> 16) & 1u);
    return (u16)(r >> 16);
}
__device__ __forceinline__ unsigned int pk2(float a, float b) {
    __hip_bfloat162 t = __float22bfloat162_rn(float2{a, b});
    unsigned int u; __builtin_memcpy(&u, &t, 4); return u;
}
// async global->LDS, 16B per lane; LDS dest = wave-uniform base + lane*16
__device__ __forceinline__ void async16(const u16* g, u16* l) {
    __builtin_amdgcn_global_load_lds((const __attribute__((address_space(1))) unsigned int*)g,
                                     (__attribute__((address_space(3))) unsigned int*)l,
                                     16, 0, 0);
}

// ---------------------------------------------------------------------------
// Kernel 1: x = inputs(fp32) + sinusoidal PE  ->  bf16 x.
// ---------------------------------------------------------------------------
__global__ __launch_bounds__(256) void pe_add_kernel(const float* __restrict__ in,
                                                     u16* __restrict__ x) {
    int idx = blockIdx.x * 256 + threadIdx.x;      // pair index, total B*N*C/2
    int cp  = idx & 511;                            // C/2 = 512 pairs per row
    int row = idx >> 9;                             // b*N + n
    int n   = row & (N_ - 1);
    float r = exp2f(-13.287712379549449f * ((float)cp * (1.0f / 512.0f)));
    float ang = (float)n * r;
    float s, c;
    sincosf(ang, &s, &c);
    float2 pr = ((const float2*)in)[idx];
    unsigned int o = ((unsigned int)f2b(pr.y + c) << 16) | (unsigned int)f2b(pr.x + s);
    ((unsigned int*)x)[idx] = o;
}

// ---------------------------------------------------------------------------
// Kernel 2: transpose W_qkv fp32 [1024][3072] -> bf16 Wt [3072][1024].
// ---------------------------------------------------------------------------
__global__ __launch_bounds__(256) void wt_kernel(const float* __restrict__ W,
                                                 u16* __restrict__ Wt) {
    __shared__ u16 tile[32][33];
    int bx = blockIdx.x;            // over 3072/32 = 96
    int by = blockIdx.y;            // over 1024/32 = 32
    int tx = threadIdx.x & 31;
    int ty = threadIdx.x >> 5;      // 0..7
    for (int i = 0; i < 32; i += 8)
        tile[ty + i][tx] = f2b(W[(size_t)(by * 32 + ty + i) * 3072 + bx * 32 + tx]);
    __syncthreads();
    for (int i = 0; i < 32; i += 8)
        Wt[(size_t)(bx * 32 + ty + i) * 1024 + by * 32 + tx] = tile[tx][ty + i];
}

// ---------------------------------------------------------------------------
// Kernel 3: QKV GEMM (unchanged this round — m97-style async staging).
// ---------------------------------------------------------------------------
__global__ __launch_bounds__(256) void qkv_gemm_kernel(const u16* __restrict__ X,
                                                       const u16* __restrict__ Wt,
                                                       u16* __restrict__ q,
                                                       u16* __restrict__ k,
                                                       u16* __restrict__ vt) {
    __shared__ u16 As[128 * 32];
    __shared__ u16 Bs[128 * 32];
    int tid  = threadIdx.x;
    int wave = tid >> 6, lane = tid & 63, l15 = lane & 15, quad = lane >> 4;
    int m0 = blockIdx.x * 128;
    int n0 = blockIdx.y * 128;
    int wm = (wave & 1) * 64;
    int wn = (wave >> 1) * 64;

    floatx4 acc[4][4];
    for (int i = 0; i < 4; i++)
        for (int j = 0; j < 4; j++)
            acc[i][j] = floatx4{0.f, 0.f, 0.f, 0.f};

    int rowOff = wave * 32 + (lane >> 2);
    int colOff = (lane & 3) * 8;
    const u16* gA = X  + (size_t)(m0 + rowOff) * 1024 + colOff;
    const u16* gB = Wt + (size_t)(n0 + rowOff) * 1024 + colOff;
    u16* lA = As + wave * 1024;
    u16* lB = Bs + wave * 1024;

    for (int k0 = 0; k0 < 1024; k0 += 32) {
        __syncthreads();
        async16(gA + k0,             lA);
        async16(gA + k0 + 16 * 1024, lA + 512);
        async16(gB + k0,             lB);
        async16(gB + k0 + 16 * 1024, lB + 512);
        __syncthreads();

        bf16x8 af[4], bf[4];
        for (int i = 0; i < 4; i++)
            af[i] = *(const bf16x8*)(As + (wm + i * 16 + l15) * 32 + quad * 8);
        for (int j = 0; j < 4; j++)
            bf[j] = *(const bf16x8*)(Bs + (wn + j * 16 + l15) * 32 + quad * 8);
        for (int i = 0; i < 4; i++)
            for (int j = 0; j < 4; j++)
                acc[i][j] = __builtin_amdgcn_mfma_f32_16x16x32_bf16(af[i], bf[j], acc[i][j], 0, 0, 0);
    }

    const float QSC = 0.125f * 1.44269504f;        // folded scale*log2e for q
    for (int i = 0; i < 4; i++) {
        int gm   = m0 + wm + i * 16 + quad * 4;
        int b    = gm >> 11;
        int nloc = gm & 2047;
        for (int j = 0; j < 4; j++) {
            int gn    = n0 + wn + j * 16 + l15;
            int which = gn >> 10;                  // 0=q 1=k 2=v
            int cc    = gn & 1023;
            int h     = cc >> 6;
            int d     = cc & 63;
            size_t bh = (size_t)(b * 16 + h);
            if (which == 2) {
                ushort4 w4;
                w4.x = f2b(acc[i][j][0]);
                w4.y = f2b(acc[i][j][1]);
                w4.z = f2b(acc[i][j][2]);
                w4.w = f2b(acc[i][j][3]);
                *(ushort4*)(vt + (bh * 64 + d) * 2048 + nloc) = w4;
            } else {
                u16* dst = (which == 0) ? q : k;
                float sc = (which == 0) ? QSC : 1.0f;
                for (int r = 0; r < 4; r++)
                    dst[(bh * 2048 + nloc + r) * 64 + d] = f2b(acc[i][j][r] * sc);
            }
        }
    }
}

// ---------------------------------------------------------------------------
// Kernel 4: flash attention, BARRIER-FREE.
// Block = 128 q-rows of one (b,h); wave = 32 q-rows; 64-key tiles.
// K and Vt fragments are loaded DIRECTLY from global (coalesced b128, L1-hot
// across the 4 waves) — no LDS staging, no __syncthreads at all. LDS holds
// only the per-wave P tile (S^T C-layout -> packed b64 store -> b128 A-frag
// read; same-wave dependency, compiler-inserted lgkmcnt).
// No max subtraction (|S| <= ~8, exp-safe); scale*log2e pre-folded into q.
// ---------------------------------------------------------------------------
__global__ __launch_bounds__(256, 4) void attn_kernel(const u16* __restrict__ q,
                                                      const u16* __restrict__ k,
                                                      const u16* __restrict__ vt,
                                                      const float* __restrict__ mask,
                                                      float* __restrict__ out) {
    __shared__ u16 Ps[4][32 * 72];    // per-wave [q][key]; 18.4 KB total

    int tid  = threadIdx.x;
    int wave = tid >> 6, lane = tid & 63, l15 = lane & 15, quad = lane >> 4;
    int bh = blockIdx.y, b = bh >> 4, h = bh & 15;
    size_t base = (size_t)bh * (N_ * 64);
    int q0 = blockIdx.x * 128 + wave * 32;
    const float* mkb = mask + b * N_;

    // Q as B-operand fragments (q pre-scaled by 0.125*log2e at GEMM time)
    bf16x8 qf[2][2];
    for (int s = 0; s < 2; s++)
        for (int dc = 0; dc < 2; dc++)
            qf[s][dc] = *(const bf16x8*)(q + base + (size_t)(q0 + s * 16 + l15) * 64 + dc * 32 + quad * 8);

    const float L2E = 1.44269504f;
    float nmq[2];
    nmq[0] = -L2E * mkb[q0 + l15];
    nmq[1] = -L2E * mkb[q0 + 16 + l15];

    floatx4 acc[2][4];
    for (int s = 0; s < 2; s++)
        for (int dt = 0; dt < 4; dt++)
            acc[s][dt] = floatx4{0.f, 0.f, 0.f, 0.f};
    float lp[2] = {0.f, 0.f};

    u16* Pw = Ps[wave];
    // per-lane global fragment bases
    const u16* kfb = k  + base + (size_t)l15 * 64 + quad * 8;                 // + (kt+t*16)*64
    const u16* vfb = vt + ((size_t)bh * 64 + l15) * 2048 + quad * 8;          // + dt*16*2048 + kt

    for (int kt = 0; kt < N_; kt += 64) {
        // S^T tiles + softmax (no max subtraction)
        for (int t = 0; t < 4; t++) {
            const u16* kp = kfb + (size_t)(kt + t * 16) * 64;
            bf16x8 kf0 = *(const bf16x8*)(kp);
            bf16x8 kf1 = *(const bf16x8*)(kp + 32);
            float4 mkv = *(const float4*)(mkb + kt + t * 16 + quad * 4);
            for (int s = 0; s < 2; s++) {
                floatx4 sa = floatx4{0.f, 0.f, 0.f, 0.f};
                sa = __builtin_amdgcn_mfma_f32_16x16x32_bf16(kf0, qf[s][0], sa, 0, 0, 0);
                sa = __builtin_amdgcn_mfma_f32_16x16x32_bf16(kf1, qf[s][1], sa, 0, 0, 0);
                float p0 = exp2f(fmaf(nmq[s], mkv.x, sa[0]));
                float p1 = exp2f(fmaf(nmq[s], mkv.y, sa[1]));
                float p2 = exp2f(fmaf(nmq[s], mkv.z, sa[2]));
                float p3 = exp2f(fmaf(nmq[s], mkv.w, sa[3]));
                lp[s] += (p0 + p1) + (p2 + p3);
                uint2 w; w.x = pk2(p0, p1); w.y = pk2(p2, p3);
                *(uint2*)(Pw + (s * 16 + l15) * 72 + t * 16 + quad * 4) = w;
            }
        }

        // PV: P from LDS (A-frags), V fragments direct from global vt
        bf16x8 pf[2][2];
        for (int s = 0; s < 2; s++) {
            pf[s][0] = *(const bf16x8*)(Pw + (s * 16 + l15) * 72 + quad * 8);
            pf[s][1] = *(const bf16x8*)(Pw + (s * 16 + l15) * 72 + 32 + quad * 8);
        }
        for (int dt = 0; dt < 4; dt++) {
            const u16* vp = vfb + (size_t)dt * 16 * 2048 + kt;
            bf16x8 vf0 = *(const bf16x8*)(vp);
            bf16x8 vf1 = *(const bf16x8*)(vp + 32);
            for (int s = 0; s < 2; s++) {
                acc[s][dt] = __builtin_amdgcn_mfma_f32_16x16x32_bf16(pf[s][0], vf0, acc[s][dt], 0, 0, 0);
                acc[s][dt] = __builtin_amdgcn_mfma_f32_16x16x32_bf16(pf[s][1], vf1, acc[s][dt], 0, 0, 0);
            }
        }
    }

    // l reduction (once) + epilogue.  acc C-layout: col=l15=d, row=quad*4+r=q
    for (int s = 0; s < 2; s++) {
        float lf = lp[s];
        lf += __shfl_xor(lf, 16);
        lf += __shfl_xor(lf, 32);
        float invl = 1.0f / lf;                // lane l15 holds inv-l of q=s*16+l15
        for (int r = 0; r < 4; r++) {
            float ir = __shfl(invl, (lane & 48) | (quad * 4 + r));
            int qrow = q0 + s * 16 + quad * 4 + r;
            float* orow = out + ((size_t)(b * N_ + qrow)) * C_ + h * 64;
            for (int dt = 0; dt < 4; dt++)
                orow[dt * 16 + l15] = acc[s][dt][r] * ir;
        }
    }
}

// ---------------------------------------------------------------------------
extern "C" void kernel_launch(void* const* d_in, const int* in_sizes, int n_in,
                              void* d_out, int out_size, void* d_ws, size_t ws_size,
                              hipStream_t stream) {
    const float* inp  = (const float*)d_in[0];   // inputs  [B,N,C] fp32
    const float* mask = (const float*)d_in[1];   // mask    [B,N]   fp32
    const float* W    = (const float*)d_in[2];   // W_qkv   [C,3C]  fp32
    float* out = (float*)d_out;                  // [B,N,C] fp32

    char* ws = (char*)d_ws;
    u16* x  = (u16*)ws;                              // 16 MB  x=in+PE bf16
    u16* Wt = (u16*)(ws + 16777216);                 // 6 MB   W^T bf16
    u16* q  = (u16*)(ws + 23068672);                 // [B,H,N,64] bf16 (pre-scaled)
    u16* k  = q + 8388608;
    u16* vt = k + 8388608;                           // [B,H,64,N] bf16 (v transposed)

    pe_add_kernel<<<16384, 256, 0, stream>>>(inp, x);
    wt_kernel<<<dim3(96, 32), 256, 0, stream>>>(W, Wt);
    qkv_gemm_kernel<<<dim3(64, 24), 256, 0, stream>>>(x, Wt, q, k, vt);
    attn_kernel<<<dim3(16, 64), 256, 0, stream>>>(q, k, vt, mask, out);
}

// Round 7
// 270.204 us; speedup vs baseline: 1.5169x; 1.5169x over previous
//
#include <hip/hip_runtime.h>
#include <hip/hip_bf16.h>

typedef unsigned short u16;
typedef __bf16 bf16x8 __attribute__((ext_vector_type(8)));
typedef float floatx4 __attribute__((ext_vector_type(4)));

#define B_ 4
#define N_ 2048
#define C_ 1024
#define H_ 16
#define HD_ 64

__device__ __forceinline__ float b2f(u16 u) {
    union { float f; unsigned int i; } v; v.i = ((unsigned int)u) << 16; return v.f;
}
__device__ __forceinline__ u16 f2b(float f) {
    union { float f; unsigned int i; } v; v.f = f;
    unsigned int i = v.i;
    unsigned int r = i + 0x7FFFu + ((i >> 16) & 1u);
    return (u16)(r >> 16);
}
__device__ __forceinline__ unsigned int pk2(float a, float b) {
    __hip_bfloat162 t = __float22bfloat162_rn(float2{a, b});
    unsigned int u; __builtin_memcpy(&u, &t, 4); return u;
}
// async global->LDS, 16B per lane; LDS dest = wave-uniform base + lane*16
__device__ __forceinline__ void async16(const u16* g, u16* l) {
    __builtin_amdgcn_global_load_lds((const __attribute__((address_space(1))) unsigned int*)g,
                                     (__attribute__((address_space(3))) unsigned int*)l,
                                     16, 0, 0);
}

// ---------------------------------------------------------------------------
// Kernel 1: x = inputs(fp32) + sinusoidal PE  ->  bf16 x.
// ---------------------------------------------------------------------------
__global__ __launch_bounds__(256) void pe_add_kernel(const float* __restrict__ in,
                                                     u16* __restrict__ x) {
    int idx = blockIdx.x * 256 + threadIdx.x;      // pair index, total B*N*C/2
    int cp  = idx & 511;                            // C/2 = 512 pairs per row
    int row = idx >> 9;                             // b*N + n
    int n   = row & (N_ - 1);
    float r = exp2f(-13.287712379549449f * ((float)cp * (1.0f / 512.0f)));
    float ang = (float)n * r;
    float s, c;
    sincosf(ang, &s, &c);
    float2 pr = ((const float2*)in)[idx];
    unsigned int o = ((unsigned int)f2b(pr.y + c) << 16) | (unsigned int)f2b(pr.x + s);
    ((unsigned int*)x)[idx] = o;
}

// ---------------------------------------------------------------------------
// Kernel 2: transpose W_qkv fp32 [1024][3072] -> bf16 Wt [3072][1024].
// ---------------------------------------------------------------------------
__global__ __launch_bounds__(256) void wt_kernel(const float* __restrict__ W,
                                                 u16* __restrict__ Wt) {
    __shared__ u16 tile[32][33];
    int bx = blockIdx.x;            // over 3072/32 = 96
    int by = blockIdx.y;            // over 1024/32 = 32
    int tx = threadIdx.x & 31;
    int ty = threadIdx.x >> 5;      // 0..7
    for (int i = 0; i < 32; i += 8)
        tile[ty + i][tx] = f2b(W[(size_t)(by * 32 + ty + i) * 3072 + bx * 32 + tx]);
    __syncthreads();
    for (int i = 0; i < 32; i += 8)
        Wt[(size_t)(bx * 32 + ty + i) * 1024 + by * 32 + tx] = tile[tx][ty + i];
}

// ---------------------------------------------------------------------------
// Kernel 3: QKV GEMM, BK=64: 16 barrier pairs instead of 32 (2x MFMA per
// barrier drain).  LDS rows are 128B; bank spread restored by XOR-swizzling
// the 16B chunk index through the GLOBAL source address (LDS dest of
// global_load_lds must stay lane-linear).  Frag-read addresses loop-invariant.
// q written pre-scaled by 0.125*log2e; v written transposed into vt.
// ---------------------------------------------------------------------------
__global__ __launch_bounds__(256) void qkv_gemm_kernel(const u16* __restrict__ X,
                                                       const u16* __restrict__ Wt,
                                                       u16* __restrict__ q,
                                                       u16* __restrict__ k,
                                                       u16* __restrict__ vt) {
    __shared__ u16 As[128 * 64];
    __shared__ u16 Bs[128 * 64];
    int tid  = threadIdx.x;
    int wave = tid >> 6, lane = tid & 63, l15 = lane & 15, quad = lane >> 4;
    int m0 = blockIdx.x * 128;
    int n0 = blockIdx.y * 128;
    int wm = (wave & 1) * 64;
    int wn = (wave >> 1) * 64;

    floatx4 acc[4][4];
    for (int i = 0; i < 4; i++)
        for (int j = 0; j < 4; j++)
            acc[i][j] = floatx4{0.f, 0.f, 0.f, 0.f};

    // staging: wave stages rows [wave*32, wave*32+32), 4 instrs of 8 rows each.
    // LDS[r][c'] = global[r][c' ^ (r&7)]  (c' = lane&7, r&7 = lane>>3)
    int rowOff = wave * 32 + (lane >> 3);
    int colSw  = ((lane & 7) ^ (lane >> 3)) * 8;
    const u16* gA = X  + (size_t)(m0 + rowOff) * 1024 + colSw;
    const u16* gB = Wt + (size_t)(n0 + rowOff) * 1024 + colSw;
    u16* lA = As + wave * 2048;                    // 32 rows * 64 elems
    u16* lB = Bs + wave * 2048;

    // loop-invariant frag read offsets: chunk g=kh*4+quad stored at g^(l15&7)
    int swl = l15 & 7;
    int aB0 = (wm + l15) * 64 + ((quad ^ swl) * 8);
    int aB1 = (wm + l15) * 64 + (((4 + quad) ^ swl) * 8);
    int bB0 = (wn + l15) * 64 + ((quad ^ swl) * 8);
    int bB1 = (wn + l15) * 64 + (((4 + quad) ^ swl) * 8);

    for (int k0 = 0; k0 < 1024; k0 += 64) {
        __syncthreads();                            // prev tile consumed
        async16(gA + k0,             lA);
        async16(gA + k0 +  8 * 1024, lA + 512);
        async16(gA + k0 + 16 * 1024, lA + 1024);
        async16(gA + k0 + 24 * 1024, lA + 1536);
        async16(gB + k0,             lB);
        async16(gB + k0 +  8 * 1024, lB + 512);
        async16(gB + k0 + 16 * 1024, lB + 1024);
        async16(gB + k0 + 24 * 1024, lB + 1536);
        __syncthreads();                            // vmcnt(0) drain + barrier

        bf16x8 af[4][2], bf[4][2];
        for (int i = 0; i < 4; i++) {
            af[i][0] = *(const bf16x8*)(As + aB0 + i * 16 * 64);
            af[i][1] = *(const bf16x8*)(As + aB1 + i * 16 * 64);
        }
        for (int j = 0; j < 4; j++) {
            bf[j][0] = *(const bf16x8*)(Bs + bB0 + j * 16 * 64);
            bf[j][1] = *(const bf16x8*)(Bs + bB1 + j * 16 * 64);
        }
        for (int i = 0; i < 4; i++)
            for (int j = 0; j < 4; j++) {
                acc[i][j] = __builtin_amdgcn_mfma_f32_16x16x32_bf16(af[i][0], bf[j][0], acc[i][j], 0, 0, 0);
                acc[i][j] = __builtin_amdgcn_mfma_f32_16x16x32_bf16(af[i][1], bf[j][1], acc[i][j], 0, 0, 0);
            }
    }

    // epilogue: C[m][n], m = m0+wm+i*16+quad*4+r, n_col = n0+wn+j*16+l15
    const float QSC = 0.125f * 1.44269504f;        // folded scale*log2e for q
    for (int i = 0; i < 4; i++) {
        int gm   = m0 + wm + i * 16 + quad * 4;
        int b    = gm >> 11;                       // / 2048
        int nloc = gm & 2047;
        for (int j = 0; j < 4; j++) {
            int gn    = n0 + wn + j * 16 + l15;
            int which = gn >> 10;                  // 0=q 1=k 2=v (wave-uniform)
            int cc    = gn & 1023;
            int h     = cc >> 6;
            int d     = cc & 63;
            size_t bh = (size_t)(b * 16 + h);
            if (which == 2) {
                ushort4 w4;
                w4.x = f2b(acc[i][j][0]);
                w4.y = f2b(acc[i][j][1]);
                w4.z = f2b(acc[i][j][2]);
                w4.w = f2b(acc[i][j][3]);
                *(ushort4*)(vt + (bh * 64 + d) * 2048 + nloc) = w4;  // 4 consecutive n
            } else {
                u16* dst = (which == 0) ? q : k;
                float sc = (which == 0) ? QSC : 1.0f;
                for (int r = 0; r < 4; r++)
                    dst[(bh * 2048 + nloc + r) * 64 + d] = f2b(acc[i][j][r] * sc);
            }
        }
    }
}

// ---------------------------------------------------------------------------
// Kernel 4: flash attention (R5 structure — LDS-staged K/V, proven 130 us).
// Block = 128 q-rows of one (b,h); wave = 32 q-rows; 64-key tiles.
// S^T = K.Q^T (C-layout col=q, row=key) -> packed ds_write_b64 P-store.
// No max subtraction (|S| <= ~8, exp-safe); scale*log2e pre-folded into q.
// ---------------------------------------------------------------------------
__global__ __launch_bounds__(256, 4) void attn_kernel(const u16* __restrict__ q,
                                                      const u16* __restrict__ k,
                                                      const u16* __restrict__ vt,
                                                      const float* __restrict__ mask,
                                                      float* __restrict__ out) {
    __shared__ u16 Ks[64 * 72];       // [key][d]
    __shared__ u16 Vs[64 * 72];       // [d][key]
    __shared__ u16 Ps[4][32 * 72];    // per-wave [q][key]

    int tid  = threadIdx.x;
    int wave = tid >> 6, lane = tid & 63, l15 = lane & 15, quad = lane >> 4;
    int bh = blockIdx.y, b = bh >> 4, h = bh & 15;
    size_t base = (size_t)bh * (N_ * 64);
    int q0 = blockIdx.x * 128 + wave * 32;
    const float* mkb = mask + b * N_;

    // Q as B-operand fragments (q pre-scaled by 0.125*log2e at GEMM time)
    bf16x8 qf[2][2];
    for (int s = 0; s < 2; s++)
        for (int dc = 0; dc < 2; dc++)
            qf[s][dc] = *(const bf16x8*)(q + base + (size_t)(q0 + s * 16 + l15) * 64 + dc * 32 + quad * 8);

    const float L2E = 1.44269504f;
    float nmq[2];
    nmq[0] = -L2E * mkb[q0 + l15];
    nmq[1] = -L2E * mkb[q0 + 16 + l15];

    floatx4 acc[2][4];
    for (int s = 0; s < 2; s++)
        for (int dt = 0; dt < 4; dt++)
            acc[s][dt] = floatx4{0.f, 0.f, 0.f, 0.f};
    float lp[2] = {0.f, 0.f};

    int r_st = tid >> 2;            // 0..63
    int c_st = (tid & 3) * 16;      // u16 col: 0,16,32,48
    u16* Pw = Ps[wave];

    for (int kt = 0; kt < N_; kt += 64) {
        int4 ka = *(const int4*)(k  + base + (size_t)(kt + r_st) * 64 + c_st);
        int4 kb = *(const int4*)(k  + base + (size_t)(kt + r_st) * 64 + c_st + 8);
        int4 va = *(const int4*)(vt + ((size_t)bh * 64 + r_st) * 2048 + kt + c_st);
        int4 vb = *(const int4*)(vt + ((size_t)bh * 64 + r_st) * 2048 + kt + c_st + 8);
        float4 mkv[4];
        for (int t = 0; t < 4; t++)
            mkv[t] = *(const float4*)(mkb + kt + t * 16 + quad * 4);
        __syncthreads();
        *(int4*)(Ks + r_st * 72 + c_st)     = ka;
        *(int4*)(Ks + r_st * 72 + c_st + 8) = kb;
        *(int4*)(Vs + r_st * 72 + c_st)     = va;
        *(int4*)(Vs + r_st * 72 + c_st + 8) = vb;
        __syncthreads();

        // S^T tiles + softmax (no max subtraction; q pre-scaled)
        for (int t = 0; t < 4; t++) {
            bf16x8 kf0 = *(const bf16x8*)(Ks + (t * 16 + l15) * 72 + quad * 8);
            bf16x8 kf1 = *(const bf16x8*)(Ks + (t * 16 + l15) * 72 + 32 + quad * 8);
            for (int s = 0; s < 2; s++) {
                floatx4 sa = floatx4{0.f, 0.f, 0.f, 0.f};
                sa = __builtin_amdgcn_mfma_f32_16x16x32_bf16(kf0, qf[s][0], sa, 0, 0, 0);
                sa = __builtin_amdgcn_mfma_f32_16x16x32_bf16(kf1, qf[s][1], sa, 0, 0, 0);
                float p0 = exp2f(fmaf(nmq[s], mkv[t].x, sa[0]));
                float p1 = exp2f(fmaf(nmq[s], mkv[t].y, sa[1]));
                float p2 = exp2f(fmaf(nmq[s], mkv[t].z, sa[2]));
                float p3 = exp2f(fmaf(nmq[s], mkv[t].w, sa[3]));
                lp[s] += (p0 + p1) + (p2 + p3);
                uint2 w; w.x = pk2(p0, p1); w.y = pk2(p2, p3);
                *(uint2*)(Pw + (s * 16 + l15) * 72 + t * 16 + quad * 4) = w;
            }
        }

        // PV
        bf16x8 pf[2][2];
        for (int s = 0; s < 2; s++) {
            pf[s][0] = *(const bf16x8*)(Pw + (s * 16 + l15) * 72 + quad * 8);
            pf[s][1] = *(const bf16x8*)(Pw + (s * 16 + l15) * 72 + 32 + quad * 8);
        }
        for (int dt = 0; dt < 4; dt++) {
            bf16x8 vf0 = *(const bf16x8*)(Vs + (dt * 16 + l15) * 72 + quad * 8);
            bf16x8 vf1 = *(const bf16x8*)(Vs + (dt * 16 + l15) * 72 + 32 + quad * 8);
            for (int s = 0; s < 2; s++) {
                acc[s][dt] = __builtin_amdgcn_mfma_f32_16x16x32_bf16(pf[s][0], vf0, acc[s][dt], 0, 0, 0);
                acc[s][dt] = __builtin_amdgcn_mfma_f32_16x16x32_bf16(pf[s][1], vf1, acc[s][dt], 0, 0, 0);
            }
        }
    }

    // l reduction (once) + epilogue.  acc C-layout: col=l15=d, row=quad*4+r=q
    for (int s = 0; s < 2; s++) {
        float lf = lp[s];
        lf += __shfl_xor(lf, 16);
        lf += __shfl_xor(lf, 32);
        float invl = 1.0f / lf;                // lane l15 holds inv-l of q=s*16+l15
        for (int r = 0; r < 4; r++) {
            float ir = __shfl(invl, (lane & 48) | (quad * 4 + r));
            int qrow = q0 + s * 16 + quad * 4 + r;
            float* orow = out + ((size_t)(b * N_ + qrow)) * C_ + h * 64;
            for (int dt = 0; dt < 4; dt++)
                orow[dt * 16 + l15] = acc[s][dt][r] * ir;
        }
    }
}

// ---------------------------------------------------------------------------
extern "C" void kernel_launch(void* const* d_in, const int* in_sizes, int n_in,
                              void* d_out, int out_size, void* d_ws, size_t ws_size,
                              hipStream_t stream) {
    const float* inp  = (const float*)d_in[0];   // inputs  [B,N,C] fp32
    const float* mask = (const float*)d_in[1];   // mask    [B,N]   fp32
    const float* W    = (const float*)d_in[2];   // W_qkv   [C,3C]  fp32
    float* out = (float*)d_out;                  // [B,N,C] fp32

    char* ws = (char*)d_ws;
    u16* x  = (u16*)ws;                              // 16 MB  x=in+PE bf16
    u16* Wt = (u16*)(ws + 16777216);                 // 6 MB   W^T bf16
    u16* q  = (u16*)(ws + 23068672);                 // [B,H,N,64] bf16 (pre-scaled)
    u16* k  = q + 8388608;
    u16* vt = k + 8388608;                           // [B,H,64,N] bf16 (v transposed)

    pe_add_kernel<<<16384, 256, 0, stream>>>(inp, x);
    wt_kernel<<<dim3(96, 32), 256, 0, stream>>>(W, Wt);
    qkv_gemm_kernel<<<dim3(64, 24), 256, 0, stream>>>(x, Wt, q, k, vt);
    attn_kernel<<<dim3(16, 64), 256, 0, stream>>>(q, k, vt, mask, out);
}